// Round 1
// baseline (353.108 us; speedup 1.0000x reference)
//
#include <hip/hip_runtime.h>
#include <math.h>

#pragma clang fp contract(off)

typedef unsigned long long u64;
typedef unsigned int u32;

#define BB 8
#define CC_TOT 1203
#define CHUNK 76
#define NCHUNK 16
#define NANC 8400
#define NSEL 1000
#define NCAND 1024

// order-preserving transform: float -> u32 with unsigned order == float order
__device__ __forceinline__ u32 okey32(float v) {
  u32 b = __float_as_uint(v);
  return (b & 0x80000000u) ? ~b : (b | 0x80000000u);
}

// sort key: (okey(logit) << 32) | (8400 - idx)  -> distinct, desc sort ties to lower idx
__device__ __forceinline__ u64 mksort(u64 finkey, int idx) {
  return (finkey & 0xFFFFFFFF00000000ull) | (u64)(u32)(NANC - idx);
}

// ---------------- kernel 1: per-anchor max/argmax over a class chunk ----------------
__global__ __launch_bounds__(256) void kmax(const float* __restrict__ cls,
                                            u64* __restrict__ fin,
                                            int hw, int anchorOff) {
  int hw4 = hw >> 2;
  int p4 = blockIdx.x * 256 + threadIdx.x;
  if (p4 >= hw4) return;
  int b = blockIdx.z;
  int c0 = blockIdx.y * CHUNK;
  int c1 = c0 + CHUNK; if (c1 > CC_TOT) c1 = CC_TOT;

  const float4* base = (const float4*)cls + (size_t)b * CC_TOT * hw4;
  float m0 = -3.4e38f, m1 = -3.4e38f, m2 = -3.4e38f, m3 = -3.4e38f;
  int i0 = c0, i1 = c0, i2 = c0, i3 = c0;
  for (int c = c0; c < c1; ++c) {
    float4 v = base[(size_t)c * hw4 + p4];
    if (v.x > m0) { m0 = v.x; i0 = c; }
    if (v.y > m1) { m1 = v.y; i1 = c; }
    if (v.z > m2) { m2 = v.z; i2 = c; }
    if (v.w > m3) { m3 = v.w; i3 = c; }
  }
  u64* dst = fin + (size_t)b * NANC + anchorOff + p4 * 4;
  atomicMax(dst + 0, ((u64)okey32(m0) << 32) | (u64)(u32)~(u32)i0);
  atomicMax(dst + 1, ((u64)okey32(m1) << 32) | (u64)(u32)~(u32)i1);
  atomicMax(dst + 2, ((u64)okey32(m2) << 32) | (u64)(u32)~(u32)i2);
  atomicMax(dst + 3, ((u64)okey32(m3) << 32) | (u64)(u32)~(u32)i3);
}

// ---------------- kernel 2: per-image top-1000 select + sort + NMS + output ----------------
__global__ __launch_bounds__(256) void knms(const u64* __restrict__ fin,
                                            const float* __restrict__ bb0,
                                            const float* __restrict__ bb1,
                                            const float* __restrict__ bb2,
                                            float* __restrict__ out) {
  __shared__ u32 hist[256];
  __shared__ u64 prefixSh;
  __shared__ u32 rankSh;
  __shared__ u32 gcnt;
  __shared__ u64 cand[NCAND];
  __shared__ float xo1s[NCAND], yo1s[NCAND], xo2s[NCAND], yo2s[NCAND], areas[NCAND];
  __shared__ float rx1s[NCAND], ry1s[NCAND], rx2s[NCAND], ry2s[NCAND], scs[NCAND];
  __shared__ int labs[NCAND], vals[NCAND];
  __shared__ int outIdx[128];
  __shared__ int keptSh;

  int b = blockIdx.x;
  int tid = threadIdx.x;
  int lane = tid & 63;
  const u64* fk = fin + (size_t)b * NANC;

  // ---- exact radix-select of the rank-1000 (descending) key ----
  u64 prefix = 0; u32 rank = NSEL;
  for (int pass = 7; pass >= 0; --pass) {
    int shift = pass * 8;
    hist[tid] = 0;
    __syncthreads();
    u64 hiMask = (pass == 7) ? 0ull : (~0ull << (shift + 8));
    for (int i = tid; i < 8448; i += 256) {  // 33 uniform iterations (8448 = 33*256)
      u32 digit = 256u;  // sentinel: no contribution
      if (i < NANC) {
        u64 k = mksort(fk[i], i);
        if ((k & hiMask) == (prefix & hiMask)) digit = (u32)((k >> shift) & 255u);
      }
      // group lanes by 9-bit digit (incl. sentinel), one atomic per group
      u64 peers = ~0ull;
      for (int bit = 0; bit < 9; ++bit) {
        u64 bal = __ballot((digit >> bit) & 1u);
        peers &= ((digit >> bit) & 1u) ? bal : ~bal;
      }
      int leader = __ffsll((unsigned long long)peers) - 1;
      if (digit < 256u && lane == leader)
        atomicAdd(&hist[digit], (u32)__popcll((unsigned long long)peers));
    }
    __syncthreads();
    // parallel suffix-sum: thread d computes S = sum_{e>d} hist[e]; unique crossing wins
    {
      u32 S = 0;
      for (int e = tid + 1; e < 256; ++e) S += hist[e];
      if (S < rank && S + hist[tid] >= rank) {
        prefixSh = prefix | ((u64)(u32)tid << shift);
        rankSh = rank - S;
      }
    }
    __syncthreads();
    prefix = prefixSh; rank = rankSh;
    __syncthreads();
  }
  u64 K = prefix;  // exact rank-1000 key (all keys distinct)

  // ---- gather the exact top-1000 (unsorted) into LDS ----
  if (tid == 0) gcnt = 0;
  for (int i = tid; i < NCAND; i += 256) cand[i] = 0ull;
  __syncthreads();
  for (int i = tid; i < 8448; i += 256) {
    bool sel = false; u64 k = 0ull;
    if (i < NANC) { k = mksort(fk[i], i); sel = (k >= K); }
    u64 mask = __ballot(sel);
    if (mask) {
      int leader = __ffsll((unsigned long long)mask) - 1;
      u32 basep = 0;
      if (lane == leader) basep = atomicAdd(&gcnt, (u32)__popcll((unsigned long long)mask));
      basep = __shfl(basep, leader);
      if (sel) {
        u32 off = (u32)__popcll((unsigned long long)(mask & ((1ull << lane) - 1ull)));
        u32 pos = basep + off;
        if (pos < NCAND) cand[pos] = k;
      }
    }
  }
  __syncthreads();

  // ---- bitonic sort descending (1024, pads=0 sink to bottom) ----
  for (u32 k2 = 2; k2 <= NCAND; k2 <<= 1) {
    for (u32 j = k2 >> 1; j > 0; j >>= 1) {
      for (u32 idx = tid; idx < NCAND; idx += 256) {
        u32 ixj = idx ^ j;
        if (ixj > idx) {
          u64 a = cand[idx], c2 = cand[ixj];
          bool sw = ((idx & k2) == 0) ? (a < c2) : (a > c2);
          if (sw) { cand[idx] = c2; cand[ixj] = a; }
        }
      }
      __syncthreads();
    }
  }

  // ---- per-candidate info: decode box, offset box, area, score, label, valid ----
  for (int s = tid; s < NSEL; s += 256) {
    u64 k = cand[s];
    int idx = NANC - (int)(u32)(k & 0xFFFFFFFFull);
    u32 ok = (u32)(k >> 32);
    u32 fb = (ok & 0x80000000u) ? (ok & 0x7FFFFFFFu) : ~ok;
    float logit = __uint_as_float(fb);
    float sc = 1.0f / (1.0f + expf(-logit));
    int label = (int)~(u32)(fk[idx] & 0xFFFFFFFFull);

    int w, str, off, hwl; const float* bb;
    if (idx < 6400)      { w = 80; str = 8;  off = 0;    hwl = 6400; bb = bb0; }
    else if (idx < 8000) { w = 40; str = 16; off = 6400; hwl = 1600; bb = bb1; }
    else                 { w = 20; str = 32; off = 8000; hwl = 400;  bb = bb2; }
    int p = idx - off;
    int y = p / w;
    int x = p - y * w;
    float fs = (float)str;
    float px = ((float)x + 0.5f) * fs;
    float py = ((float)y + 0.5f) * fs;
    const float* bp = bb + (size_t)b * 4 * hwl + p;
    float t0 = bp[0] * fs;
    float t1 = bp[hwl] * fs;
    float t2 = bp[2 * hwl] * fs;
    float t3 = bp[3 * hwl] * fs;
    float x1 = px - t0, y1 = py - t1, x2 = px + t2, y2 = py + t3;
    float lo = (float)label * 4096.0f;
    float ox1 = x1 + lo, oy1 = y1 + lo, ox2 = x2 + lo, oy2 = y2 + lo;
    float area = (ox2 - ox1) * (oy2 - oy1);  // ref computes area from OFFSET boxes

    xo1s[s] = ox1; yo1s[s] = oy1; xo2s[s] = ox2; yo2s[s] = oy2; areas[s] = area;
    rx1s[s] = x1;  ry1s[s] = y1;  rx2s[s] = x2;  ry2s[s] = y2;  scs[s] = sc;
    labs[s] = label;
    vals[s] = (sc > 0.25f) ? 1 : 0;
  }
  __syncthreads();

  // ---- greedy NMS, single wave, early exit at 100 kept ----
  if (tid < 64) {
    float ax1 = 0, ay1 = 0, ax2 = 0, ay2 = 0, aar = 0; int aon = 0;
    float bx1 = 0, by1 = 0, bx2 = 0, by2 = 0, bar = 0; int bon = 0;
    int kept = 0;
    for (int i = 0; i < NSEL; ++i) {
      if (kept >= 100) break;
      float cx1 = xo1s[i], cy1 = yo1s[i], cx2 = xo2s[i], cy2 = yo2s[i], car = areas[i];
      bool sup = false;
      if (aon) {
        float ltx = fmaxf(ax1, cx1), lty = fmaxf(ay1, cy1);
        float rbx = fminf(ax2, cx2), rby = fminf(ay2, cy2);
        float wd = fmaxf(rbx - ltx, 0.0f), ht = fmaxf(rby - lty, 0.0f);
        float inter = wd * ht;
        sup = sup || ((inter / (aar + car - inter + 1e-7f)) > 0.65f);
      }
      if (bon) {
        float ltx = fmaxf(bx1, cx1), lty = fmaxf(by1, cy1);
        float rbx = fminf(bx2, cx2), rby = fminf(by2, cy2);
        float wd = fmaxf(rbx - ltx, 0.0f), ht = fmaxf(rby - lty, 0.0f);
        float inter = wd * ht;
        sup = sup || ((inter / (bar + car - inter + 1e-7f)) > 0.65f);
      }
      bool anysup = __any(sup);
      if (vals[i] && !anysup) {
        if (kept < 64) {
          if (lane == kept) { ax1 = cx1; ay1 = cy1; ax2 = cx2; ay2 = cy2; aar = car; aon = 1; }
        } else {
          if (lane == kept - 64) { bx1 = cx1; by1 = cy1; bx2 = cx2; by2 = cy2; bar = car; bon = 1; }
        }
        if (lane == 0) outIdx[kept] = i;
        ++kept;
      }
    }
    if (lane == 0) keptSh = kept;
  }
  __syncthreads();

  // ---- write outputs: num_dets[8] | boxes[8,100,4] | scores[8,100] | labels[8,100] ----
  int kept = keptSh;
  float* o_nd = out;
  float* o_box = out + BB;
  float* o_sc = out + BB + BB * 100 * 4;
  float* o_lb = out + BB + BB * 100 * 4 + BB * 100;
  if (tid == 0) o_nd[b] = (float)kept;
  for (int s = tid; s < 100; s += 256) {
    float v0 = 0, v1 = 0, v2 = 0, v3 = 0, sv = 0, lv = -1.0f;
    if (s < kept) {
      int i = outIdx[s];
      v0 = rx1s[i]; v1 = ry1s[i]; v2 = rx2s[i]; v3 = ry2s[i];
      sv = scs[i]; lv = (float)labs[i];
    }
    float* bo = o_box + ((size_t)b * 100 + s) * 4;
    bo[0] = v0; bo[1] = v1; bo[2] = v2; bo[3] = v3;
    o_sc[b * 100 + s] = sv;
    o_lb[b * 100 + s] = lv;
  }
}

extern "C" void kernel_launch(void* const* d_in, const int* in_sizes, int n_in,
                              void* d_out, int out_size, void* d_ws, size_t ws_size,
                              hipStream_t stream) {
  const float* cls0 = (const float*)d_in[0];  // [8,1203,80,80]
  const float* bb0  = (const float*)d_in[1];  // [8,4,80,80]
  const float* cls1 = (const float*)d_in[2];  // [8,1203,40,40]
  const float* bb1  = (const float*)d_in[3];  // [8,4,40,40]
  const float* cls2 = (const float*)d_in[4];  // [8,1203,20,20]
  const float* bb2  = (const float*)d_in[5];  // [8,4,20,20]
  u64* fin = (u64*)d_ws;                       // [8][8400] packed (okey(maxlogit)<<32 | ~label)

  hipMemsetAsync(d_ws, 0, (size_t)BB * NANC * sizeof(u64), stream);

  dim3 blk(256);
  kmax<<<dim3(7, NCHUNK, BB), blk, 0, stream>>>(cls0, fin, 6400, 0);
  kmax<<<dim3(2, NCHUNK, BB), blk, 0, stream>>>(cls1, fin, 1600, 6400);
  kmax<<<dim3(1, NCHUNK, BB), blk, 0, stream>>>(cls2, fin, 400, 8000);
  knms<<<dim3(BB), blk, 0, stream>>>(fin, bb0, bb1, bb2, (float*)d_out);
}

// Round 2
// 190.773 us; speedup vs baseline: 1.8509x; 1.8509x over previous
//
#include <hip/hip_runtime.h>
#include <math.h>

#pragma clang fp contract(off)

typedef unsigned long long u64;
typedef unsigned int u32;

#define BB 8
#define CC_TOT 1203
#define NANC 8400
#define NSEL 1000
#define NCAND 1024
#define NT 1024

// order-preserving transform: float -> u32 with unsigned order == float order
__device__ __forceinline__ u32 okey32(float v) {
  u32 b = __float_as_uint(v);
  return (b & 0x80000000u) ? ~b : (b | 0x80000000u);
}

__device__ __forceinline__ float unokey32(u32 ok) {
  u32 fb = (ok & 0x80000000u) ? (ok & 0x7FFFFFFFu) : ~ok;
  return __uint_as_float(fb);
}

// 48-bit sort key: (okey(logit) << 16) | (65535 - idx); distinct, desc order ties to lower idx
__device__ __forceinline__ u64 mksort(u64 finv, int idx) {
  return ((finv >> 32) << 16) | (u64)(u32)(0xFFFFu - (u32)idx);
}

// ---------------- kernel 1: per-anchor max/argmax over a class chunk (no atomics) ----------------
__global__ __launch_bounds__(256) void kmax(const float* __restrict__ cls,
                                            u64* __restrict__ part,
                                            int hw4, int chunkSz, int anchorOff) {
  int p4 = blockIdx.x * 256 + threadIdx.x;
  if (p4 >= hw4) return;
  int b = blockIdx.z;
  int c0 = blockIdx.y * chunkSz;
  int c1 = c0 + chunkSz; if (c1 > CC_TOT) c1 = CC_TOT;

  const float4* base = (const float4*)cls + (size_t)b * CC_TOT * hw4;
  float m0 = -3.4e38f, m1 = -3.4e38f, m2 = -3.4e38f, m3 = -3.4e38f;
  int i0 = c0, i1 = c0, i2 = c0, i3 = c0;
  for (int c = c0; c < c1; ++c) {
    float4 v = base[(size_t)c * hw4 + p4];
    if (v.x > m0) { m0 = v.x; i0 = c; }
    if (v.y > m1) { m1 = v.y; i1 = c; }
    if (v.z > m2) { m2 = v.z; i2 = c; }
    if (v.w > m3) { m3 = v.w; i3 = c; }
  }
  // pack (okey(maxlogit)<<32 | ~argmax): u64 max => score desc, tie -> smaller class
  u64* dst = part + ((size_t)blockIdx.y * BB + b) * NANC + anchorOff + p4 * 4;
  dst[0] = ((u64)okey32(m0) << 32) | (u64)(u32)~(u32)i0;
  dst[1] = ((u64)okey32(m1) << 32) | (u64)(u32)~(u32)i1;
  dst[2] = ((u64)okey32(m2) << 32) | (u64)(u32)~(u32)i2;
  dst[3] = ((u64)okey32(m3) << 32) | (u64)(u32)~(u32)i3;
}

// ---------------- kernel 1b: reduce partials over chunks ----------------
__global__ __launch_bounds__(256) void kreduce(const u64* __restrict__ part,
                                               u64* __restrict__ fin, int nchunk) {
  int g = blockIdx.x * 256 + threadIdx.x;
  if (g >= BB * NANC) return;
  u64 m = part[g];
  for (int ch = 1; ch < nchunk; ++ch) {
    u64 v = part[(size_t)ch * (BB * NANC) + g];
    if (v > m) m = v;
  }
  fin[g] = m;
}

// ---------------- kernel 2: per-image top-1000 select + sort + NMS + output ----------------
__global__ __launch_bounds__(1024) void knms(const u64* __restrict__ fin,
                                             const float* __restrict__ bb0,
                                             const float* __restrict__ bb1,
                                             const float* __restrict__ bb2,
                                             float* __restrict__ out) {
  __shared__ u32 hist[4096];
  __shared__ u32 waveTot[16];
  __shared__ u32 waveSufExcl[16];
  __shared__ u64 prefixSh;
  __shared__ u32 rankSh;
  __shared__ u32 gcnt;
  __shared__ u64 cand[NCAND];
  __shared__ float xo1s[NCAND], yo1s[NCAND], xo2s[NCAND], yo2s[NCAND], areas[NCAND];
  __shared__ float rx1s[NCAND], ry1s[NCAND], rx2s[NCAND], ry2s[NCAND], scs[NCAND];
  __shared__ int labs[NCAND], vals[NCAND];
  __shared__ int outIdx[128];
  __shared__ int keptSh;

  int b = blockIdx.x;
  int tid = threadIdx.x;
  int lane = tid & 63;
  int wv = tid >> 6;
  const u64* fk = fin + (size_t)b * NANC;

  // ---- exact radix-select of the rank-1000 (descending) 48-bit key: 4 passes x 12 bits ----
  u64 prefix = 0; u32 rank = NSEL;
  for (int pass = 3; pass >= 0; --pass) {
    int shift = pass * 12;
    for (int i = tid; i < 4096; i += NT) hist[i] = 0;
    __syncthreads();
    u64 hiMask = (~0ull) << (shift + 12);  // pass 3: masks bits >=48 which are 0 on both sides
    for (int i = tid; i < NANC; i += NT) {
      u64 k = mksort(fk[i], i);
      u32 digit = 4096u;  // sentinel: no contribution
      if ((k & hiMask) == (prefix & hiMask)) digit = (u32)((k >> shift) & 4095u);
      // wave-level clustering by 13-bit digit (logits concentrate -> few hot bins;
      // plain LDS atomics would serialize ~8400 same-address RMWs)
      u64 peers = ~0ull;
      for (int bit = 0; bit < 13; ++bit) {
        u64 bal = __ballot((digit >> bit) & 1u);
        peers &= ((digit >> bit) & 1u) ? bal : ~bal;
      }
      int leader = __ffsll((unsigned long long)peers) - 1;
      if (digit < 4096u && lane == leader)
        atomicAdd(&hist[digit], (u32)__popcll((unsigned long long)peers));
    }
    __syncthreads();
    // suffix scan over 4096 bins: 4 bins/thread -> intra-wave shfl suffix -> wave totals
    u32 l0 = hist[4 * tid], l1 = hist[4 * tid + 1], l2 = hist[4 * tid + 2], l3 = hist[4 * tid + 3];
    u32 psum = l0 + l1 + l2 + l3;
    u32 x = psum;
    for (int s = 1; s < 64; s <<= 1) {
      u32 v = __shfl_down(x, s);
      if (lane + s < 64) x += v;
    }
    if (lane == 0) waveTot[wv] = x;
    __syncthreads();
    if (tid < 16) {
      u32 y = waveTot[tid];
      u32 z = y;
      for (int s = 1; s < 16; s <<= 1) {
        u32 v = __shfl_down(z, s);
        if (tid + s < 16) z += v;
      }
      waveSufExcl[tid] = z - y;
    }
    __syncthreads();
    u32 S = x + waveSufExcl[wv];   // sum of hist over bins >= 4*tid
    u32 G3 = S - psum;             // count of keys in bins > 4*tid+3
    u32 G2 = G3 + l3;
    u32 G1 = G2 + l2;
    u32 G0 = G1 + l1;
    u32 r = rank;
    if      (G3 < r && G3 + l3 >= r) { prefixSh = prefix | ((u64)(4u * tid + 3) << shift); rankSh = r - G3; }
    else if (G2 < r && G2 + l2 >= r) { prefixSh = prefix | ((u64)(4u * tid + 2) << shift); rankSh = r - G2; }
    else if (G1 < r && G1 + l1 >= r) { prefixSh = prefix | ((u64)(4u * tid + 1) << shift); rankSh = r - G1; }
    else if (G0 < r && G0 + l0 >= r) { prefixSh = prefix | ((u64)(4u * tid + 0) << shift); rankSh = r - G0; }
    __syncthreads();
    prefix = prefixSh; rank = rankSh;
    __syncthreads();
  }
  u64 K = prefix;  // exact rank-1000 key (all keys distinct) => count(key >= K) == 1000

  // ---- gather the exact top-1000 (unsorted) into LDS ----
  if (tid == 0) gcnt = 0;
  for (int i = tid; i < NCAND; i += NT) cand[i] = 0ull;
  __syncthreads();
  for (int i = tid; i < NANC; i += NT) {
    u64 k = mksort(fk[i], i);
    bool sel = (k >= K);
    u64 mask = __ballot(sel);
    if (mask) {
      int leader = __ffsll((unsigned long long)mask) - 1;
      u32 basep = 0;
      if (lane == leader) basep = atomicAdd(&gcnt, (u32)__popcll((unsigned long long)mask));
      basep = __shfl((int)basep, leader);
      if (sel) {
        u32 off = (u32)__popcll((unsigned long long)(mask & ((1ull << lane) - 1ull)));
        cand[basep + off] = k;
      }
    }
  }
  __syncthreads();

  // ---- bitonic sort descending (1024 elems, 1/thread; pads=0 sink to bottom) ----
  for (u32 k2 = 2; k2 <= NCAND; k2 <<= 1) {
    for (u32 j = k2 >> 1; j > 0; j >>= 1) {
      u32 ixj = tid ^ j;
      if (ixj > (u32)tid) {
        u64 a = cand[tid], c2 = cand[ixj];
        bool sw = ((tid & k2) == 0) ? (a < c2) : (a > c2);
        if (sw) { cand[tid] = c2; cand[ixj] = a; }
      }
      __syncthreads();
    }
  }

  // ---- per-candidate: decode box, offset box, area, score, label, valid ----
  if (tid < NSEL) {
    u64 k = cand[tid];
    int idx = 0xFFFF - (int)(u32)(k & 0xFFFFull);
    float logit = unokey32((u32)(k >> 16));
    float sc = 1.0f / (1.0f + expf(-logit));
    int label = (int)~(u32)(fk[idx] & 0xFFFFFFFFull);

    int w, str, off, hwl; const float* bb;
    if (idx < 6400)      { w = 80; str = 8;  off = 0;    hwl = 6400; bb = bb0; }
    else if (idx < 8000) { w = 40; str = 16; off = 6400; hwl = 1600; bb = bb1; }
    else                 { w = 20; str = 32; off = 8000; hwl = 400;  bb = bb2; }
    int p = idx - off;
    int y = p / w;
    int x = p - y * w;
    float fs = (float)str;
    float px = ((float)x + 0.5f) * fs;
    float py = ((float)y + 0.5f) * fs;
    const float* bp = bb + (size_t)b * 4 * hwl + p;
    float t0 = bp[0] * fs;
    float t1 = bp[hwl] * fs;
    float t2 = bp[2 * hwl] * fs;
    float t3 = bp[3 * hwl] * fs;
    float x1 = px - t0, y1 = py - t1, x2 = px + t2, y2 = py + t3;
    float lo = (float)label * 4096.0f;
    float ox1 = x1 + lo, oy1 = y1 + lo, ox2 = x2 + lo, oy2 = y2 + lo;
    float area = (ox2 - ox1) * (oy2 - oy1);  // ref computes area from OFFSET boxes

    xo1s[tid] = ox1; yo1s[tid] = oy1; xo2s[tid] = ox2; yo2s[tid] = oy2; areas[tid] = area;
    rx1s[tid] = x1;  ry1s[tid] = y1;  rx2s[tid] = x2;  ry2s[tid] = y2;  scs[tid] = sc;
    labs[tid] = label;
    vals[tid] = (sc > 0.25f) ? 1 : 0;
  }
  __syncthreads();

  // ---- greedy NMS, single wave, early exit at 100 kept ----
  if (tid < 64) {
    float ax1 = 0, ay1 = 0, ax2 = 0, ay2 = 0, aar = 0; int aon = 0;
    float bx1 = 0, by1 = 0, bx2 = 0, by2 = 0, bar = 0; int bon = 0;
    int kept = 0;
    for (int i = 0; i < NSEL; ++i) {
      if (kept >= 100) break;
      float cx1 = xo1s[i], cy1 = yo1s[i], cx2 = xo2s[i], cy2 = yo2s[i], car = areas[i];
      bool sup = false;
      if (aon) {
        float ltx = fmaxf(ax1, cx1), lty = fmaxf(ay1, cy1);
        float rbx = fminf(ax2, cx2), rby = fminf(ay2, cy2);
        float wd = fmaxf(rbx - ltx, 0.0f), ht = fmaxf(rby - lty, 0.0f);
        float inter = wd * ht;
        sup = sup || ((inter / (aar + car - inter + 1e-7f)) > 0.65f);
      }
      if (bon) {
        float ltx = fmaxf(bx1, cx1), lty = fmaxf(by1, cy1);
        float rbx = fminf(bx2, cx2), rby = fminf(by2, cy2);
        float wd = fmaxf(rbx - ltx, 0.0f), ht = fmaxf(rby - lty, 0.0f);
        float inter = wd * ht;
        sup = sup || ((inter / (bar + car - inter + 1e-7f)) > 0.65f);
      }
      bool anysup = __any(sup);
      if (vals[i] && !anysup) {
        if (kept < 64) {
          if (lane == kept) { ax1 = cx1; ay1 = cy1; ax2 = cx2; ay2 = cy2; aar = car; aon = 1; }
        } else {
          if (lane == kept - 64) { bx1 = cx1; by1 = cy1; bx2 = cx2; by2 = cy2; bar = car; bon = 1; }
        }
        if (lane == 0) outIdx[kept] = i;
        ++kept;
      }
    }
    if (lane == 0) keptSh = kept;
  }
  __syncthreads();

  // ---- write outputs: num_dets[8] | boxes[8,100,4] | scores[8,100] | labels[8,100] ----
  int kept = keptSh;
  float* o_nd = out;
  float* o_box = out + BB;
  float* o_sc = out + BB + BB * 100 * 4;
  float* o_lb = out + BB + BB * 100 * 4 + BB * 100;
  if (tid == 0) o_nd[b] = (float)kept;
  if (tid < 100) {
    int s = tid;
    float v0 = 0, v1 = 0, v2 = 0, v3 = 0, sv = 0, lv = -1.0f;
    if (s < kept) {
      int i = outIdx[s];
      v0 = rx1s[i]; v1 = ry1s[i]; v2 = rx2s[i]; v3 = ry2s[i];
      sv = scs[i]; lv = (float)labs[i];
    }
    float* bo = o_box + ((size_t)b * 100 + s) * 4;
    bo[0] = v0; bo[1] = v1; bo[2] = v2; bo[3] = v3;
    o_sc[b * 100 + s] = sv;
    o_lb[b * 100 + s] = lv;
  }
}

extern "C" void kernel_launch(void* const* d_in, const int* in_sizes, int n_in,
                              void* d_out, int out_size, void* d_ws, size_t ws_size,
                              hipStream_t stream) {
  const float* cls0 = (const float*)d_in[0];  // [8,1203,80,80]
  const float* bb0  = (const float*)d_in[1];  // [8,4,80,80]
  const float* cls1 = (const float*)d_in[2];  // [8,1203,40,40]
  const float* bb1  = (const float*)d_in[3];  // [8,4,40,40]
  const float* cls2 = (const float*)d_in[4];  // [8,1203,20,20]
  const float* bb2  = (const float*)d_in[5];  // [8,4,20,20]

  size_t finB = (size_t)BB * NANC * sizeof(u64);
  size_t planeB = (size_t)BB * NANC * sizeof(u64);

  u64* fin = (u64*)d_ws;
  int nchunk = 1;
  u64* part = fin;  // fallback: single chunk straight into fin, skip reduce
  if (ws_size >= finB + planeB) {
    size_t avail = (ws_size - finB) / planeB;
    nchunk = (int)(avail < 32 ? avail : 32);
    if (nchunk < 1) nchunk = 1;
  }
  int chunkSz = (CC_TOT + nchunk - 1) / nchunk;
  nchunk = (CC_TOT + chunkSz - 1) / chunkSz;  // no empty chunks
  bool needReduce = (nchunk > 1);
  if (needReduce) part = (u64*)((char*)d_ws + finB);

  dim3 blk(256);
  kmax<<<dim3(7, nchunk, BB), blk, 0, stream>>>(cls0, part, 1600, chunkSz, 0);
  kmax<<<dim3(2, nchunk, BB), blk, 0, stream>>>(cls1, part, 400, chunkSz, 6400);
  kmax<<<dim3(1, nchunk, BB), blk, 0, stream>>>(cls2, part, 100, chunkSz, 8000);
  if (needReduce)
    kreduce<<<dim3((BB * NANC + 255) / 256), blk, 0, stream>>>(part, fin, nchunk);
  knms<<<dim3(BB), dim3(NT), 0, stream>>>(fin, bb0, bb1, bb2, (float*)d_out);
}

// Round 3
// 175.140 us; speedup vs baseline: 2.0161x; 1.0893x over previous
//
#include <hip/hip_runtime.h>
#include <math.h>

#pragma clang fp contract(off)

typedef unsigned long long u64;
typedef unsigned int u32;

#define BB 8
#define CC_TOT 1203
#define NANC 8400
#define NSEL 1000
#define NCAND 1024
#define NT 1024

// order-preserving transform: float -> u32 with unsigned order == float order
__device__ __forceinline__ u32 okey32(float v) {
  u32 b = __float_as_uint(v);
  return (b & 0x80000000u) ? ~b : (b | 0x80000000u);
}

__device__ __forceinline__ float unokey32(u32 ok) {
  u32 fb = (ok & 0x80000000u) ? (ok & 0x7FFFFFFFu) : ~ok;
  return __uint_as_float(fb);
}

// ---------------- kernel 1: per-anchor max/argmax over a class chunk (all 3 levels fused) ----------------
__global__ __launch_bounds__(256) void kmax(const float* __restrict__ cls0,
                                            const float* __restrict__ cls1,
                                            const float* __restrict__ cls2,
                                            u64* __restrict__ part,
                                            int chunkSz) {
  int bx = blockIdx.x;  // 0..6: level0, 7..8: level1, 9: level2
  const float* cls; int hw4, aoff, xb;
  if (bx < 7)      { cls = cls0; hw4 = 1600; aoff = 0;    xb = bx; }
  else if (bx < 9) { cls = cls1; hw4 = 400;  aoff = 6400; xb = bx - 7; }
  else             { cls = cls2; hw4 = 100;  aoff = 8000; xb = 0; }
  int p4 = xb * 256 + threadIdx.x;
  if (p4 >= hw4) return;
  int b = blockIdx.z;
  int c0 = blockIdx.y * chunkSz;
  int c1 = c0 + chunkSz; if (c1 > CC_TOT) c1 = CC_TOT;

  const float4* base = (const float4*)cls + (size_t)b * CC_TOT * hw4;
  float m0 = -3.4e38f, m1 = -3.4e38f, m2 = -3.4e38f, m3 = -3.4e38f;
  int i0 = c0, i1 = c0, i2 = c0, i3 = c0;
  for (int c = c0; c < c1; ++c) {
    float4 v = base[(size_t)c * hw4 + p4];
    if (v.x > m0) { m0 = v.x; i0 = c; }
    if (v.y > m1) { m1 = v.y; i1 = c; }
    if (v.z > m2) { m2 = v.z; i2 = c; }
    if (v.w > m3) { m3 = v.w; i3 = c; }
  }
  // pack (okey(maxlogit)<<32 | ~argmax): u64 max => score desc, tie -> smaller class
  u64* dst = part + ((size_t)blockIdx.y * BB + b) * NANC + aoff + p4 * 4;
  dst[0] = ((u64)okey32(m0) << 32) | (u64)(u32)~(u32)i0;
  dst[1] = ((u64)okey32(m1) << 32) | (u64)(u32)~(u32)i1;
  dst[2] = ((u64)okey32(m2) << 32) | (u64)(u32)~(u32)i2;
  dst[3] = ((u64)okey32(m3) << 32) | (u64)(u32)~(u32)i3;
}

// ---------------- kernel 1b: reduce partials over chunks + emit final sort key ----------------
// key = (okey(logit) << 32) | ((65535 - anchorIdx) << 16) | label
// bits 16..63 are unique per key (anchor idx unique); label rides in low 16 bits as payload.
__global__ __launch_bounds__(256) void kreduce(const u64* __restrict__ part,
                                               u64* __restrict__ fin, int nchunk) {
  int i = blockIdx.x * 256 + threadIdx.x;
  if (i >= NANC) return;
  int b = blockIdx.y;
  int g = b * NANC + i;
  u64 m = part[g];
  for (int ch = 1; ch < nchunk; ++ch) {
    u64 v = part[(size_t)ch * (BB * NANC) + g];
    m = (v > m) ? v : m;
  }
  u32 lab = ~(u32)m;  // argmax class, < 1203
  fin[g] = (m & 0xFFFFFFFF00000000ull) | ((u64)(u32)(0xFFFFu - (u32)i) << 16) | (u64)lab;
}

// ---------------- kernel 2: per-image top-1000 select + rank-sort + NMS + output ----------------
struct DecodeArrays {
  float xo1[NCAND], yo1[NCAND], xo2[NCAND], yo2[NCAND], ar[NCAND];
  float rx1[NCAND], ry1[NCAND], rx2[NCAND], ry2[NCAND], sc[NCAND];
  int lab[NCAND], val[NCAND];
};

__global__ __launch_bounds__(1024) void knms(const u64* __restrict__ fin,
                                             const float* __restrict__ bb0,
                                             const float* __restrict__ bb1,
                                             const float* __restrict__ bb2,
                                             float* __restrict__ out) {
  __shared__ union ShU {
    u64 fk[NANC];      // 67,200 B — dead after gather
    DecodeArrays d;    // 49,152 B — aliases fk
  } sh;
  __shared__ u32 hist[4096];
  __shared__ u32 waveTot[16];
  __shared__ u32 waveSufExcl[16];
  __shared__ u64 prefixSh;
  __shared__ u32 rankSh;
  __shared__ u32 gcnt;
  __shared__ u64 cand[NCAND];
  __shared__ int outIdx[128];
  __shared__ int keptSh;

  int b = blockIdx.x;
  int tid = threadIdx.x;
  int lane = tid & 63;
  int wv = tid >> 6;

  // ---- stage the 8400 pre-built sort keys into LDS ----
  {
    const u64* fk = fin + (size_t)b * NANC;
    for (int i = tid; i < NANC; i += NT) sh.fk[i] = fk[i];
  }
  __syncthreads();

  // ---- exact radix-select of the rank-1000 (descending) key over bits [16,64): 4 x 12-bit ----
  u64 prefix = 0; u32 rank = NSEL;
  for (int pass = 3; pass >= 0; --pass) {
    int shift = 16 + pass * 12;
    for (int i = tid; i < 4096; i += NT) hist[i] = 0;
    __syncthreads();
    u64 hiMask = (pass == 3) ? 0ull : ((~0ull) << (shift + 12));
    for (int i = tid; i < NANC; i += NT) {
      u64 k = sh.fk[i];
      u32 digit = 4096u;  // sentinel: no contribution
      if ((k & hiMask) == (prefix & hiMask)) digit = (u32)((k >> shift) & 4095u);
      // wave-level clustering by 13-bit digit (top pass concentrates into few bins;
      // plain LDS atomics would serialize same-address RMWs)
      u64 peers = ~0ull;
      for (int bit = 0; bit < 13; ++bit) {
        u64 bal = __ballot((digit >> bit) & 1u);
        peers &= ((digit >> bit) & 1u) ? bal : ~bal;
      }
      int leader = __ffsll((unsigned long long)peers) - 1;
      if (digit < 4096u && lane == leader)
        atomicAdd(&hist[digit], (u32)__popcll((unsigned long long)peers));
    }
    __syncthreads();
    // suffix scan over 4096 bins: 4 bins/thread -> intra-wave shfl suffix -> wave totals
    u32 l0 = hist[4 * tid], l1 = hist[4 * tid + 1], l2 = hist[4 * tid + 2], l3 = hist[4 * tid + 3];
    u32 psum = l0 + l1 + l2 + l3;
    u32 x = psum;
    for (int s = 1; s < 64; s <<= 1) {
      u32 v = __shfl_down(x, s);
      if (lane + s < 64) x += v;
    }
    if (lane == 0) waveTot[wv] = x;
    __syncthreads();
    if (tid < 16) {
      u32 y = waveTot[tid];
      u32 z = y;
      for (int s = 1; s < 16; s <<= 1) {
        u32 v = __shfl_down(z, s);
        if (tid + s < 16) z += v;
      }
      waveSufExcl[tid] = z - y;
    }
    __syncthreads();
    u32 S = x + waveSufExcl[wv];   // sum of hist over bins >= 4*tid
    u32 G3 = S - psum;             // count of keys in bins > 4*tid+3
    u32 G2 = G3 + l3;
    u32 G1 = G2 + l2;
    u32 G0 = G1 + l1;
    u32 r = rank;
    if      (G3 < r && G3 + l3 >= r) { prefixSh = prefix | ((u64)(4u * tid + 3) << shift); rankSh = r - G3; }
    else if (G2 < r && G2 + l2 >= r) { prefixSh = prefix | ((u64)(4u * tid + 2) << shift); rankSh = r - G2; }
    else if (G1 < r && G1 + l1 >= r) { prefixSh = prefix | ((u64)(4u * tid + 1) << shift); rankSh = r - G1; }
    else if (G0 < r && G0 + l0 >= r) { prefixSh = prefix | ((u64)(4u * tid + 0) << shift); rankSh = r - G0; }
    __syncthreads();
    prefix = prefixSh; rank = rankSh;
    __syncthreads();
  }
  u64 K = prefix;  // exact rank-1000 key threshold (low 16 bits zero) => count(key >= K) == 1000

  // ---- gather the exact top-1000 (unsorted) into cand ----
  if (tid == 0) gcnt = 0;
  __syncthreads();
  for (int i = tid; i < NANC; i += NT) {
    u64 k = sh.fk[i];
    bool sel = (k >= K);
    u64 mask = __ballot(sel);
    if (mask) {
      int leader = __ffsll((unsigned long long)mask) - 1;
      u32 basep = 0;
      if (lane == leader) basep = atomicAdd(&gcnt, (u32)__popcll((unsigned long long)mask));
      basep = __shfl((int)basep, leader);
      if (sel) {
        u32 off = (u32)__popcll((unsigned long long)(mask & ((1ull << lane) - 1ull)));
        u32 pos = basep + off;
        if (pos < NCAND) cand[pos] = k;
      }
    }
  }
  __syncthreads();  // fk dead from here; sh.d may be written

  // ---- rank-by-comparison sort + decode + scatter by rank ----
  if (tid < NSEL) {
    u64 my = cand[tid];
    int rk = 0;
    for (int j = 0; j < NSEL; ++j) {  // broadcast LDS reads, conflict-free
      rk += (cand[j] > my) ? 1 : 0;
    }
    // decode this candidate
    int label = (int)(u32)(my & 0xFFFFull);
    int idx = 0xFFFF - (int)(u32)((my >> 16) & 0xFFFFull);
    float logit = unokey32((u32)(my >> 32));
    float sc = 1.0f / (1.0f + expf(-logit));

    int w, str, off, hwl; const float* bb;
    if (idx < 6400)      { w = 80; str = 8;  off = 0;    hwl = 6400; bb = bb0; }
    else if (idx < 8000) { w = 40; str = 16; off = 6400; hwl = 1600; bb = bb1; }
    else                 { w = 20; str = 32; off = 8000; hwl = 400;  bb = bb2; }
    int p = idx - off;
    int y = p / w;
    int x = p - y * w;
    float fs = (float)str;
    float px = ((float)x + 0.5f) * fs;
    float py = ((float)y + 0.5f) * fs;
    const float* bp = bb + (size_t)b * 4 * hwl + p;
    float t0 = bp[0] * fs;
    float t1 = bp[hwl] * fs;
    float t2 = bp[2 * hwl] * fs;
    float t3 = bp[3 * hwl] * fs;
    float x1 = px - t0, y1 = py - t1, x2 = px + t2, y2 = py + t3;
    float lo = (float)label * 4096.0f;
    float ox1 = x1 + lo, oy1 = y1 + lo, ox2 = x2 + lo, oy2 = y2 + lo;
    float area = (ox2 - ox1) * (oy2 - oy1);  // ref computes area from OFFSET boxes

    sh.d.xo1[rk] = ox1; sh.d.yo1[rk] = oy1; sh.d.xo2[rk] = ox2; sh.d.yo2[rk] = oy2; sh.d.ar[rk] = area;
    sh.d.rx1[rk] = x1;  sh.d.ry1[rk] = y1;  sh.d.rx2[rk] = x2;  sh.d.ry2[rk] = y2;  sh.d.sc[rk] = sc;
    sh.d.lab[rk] = label;
    sh.d.val[rk] = (sc > 0.25f) ? 1 : 0;
  }
  __syncthreads();

  // ---- greedy NMS, single wave, early exit at 100 kept ----
  if (tid < 64) {
    float ax1 = 0, ay1 = 0, ax2 = 0, ay2 = 0, aar = 0; int aon = 0;
    float bx1 = 0, by1 = 0, bx2 = 0, by2 = 0, bar = 0; int bon = 0;
    int kept = 0;
    for (int i = 0; i < NSEL; ++i) {
      if (kept >= 100) break;
      float cx1 = sh.d.xo1[i], cy1 = sh.d.yo1[i], cx2 = sh.d.xo2[i], cy2 = sh.d.yo2[i], car = sh.d.ar[i];
      bool sup = false;
      if (aon) {
        float ltx = fmaxf(ax1, cx1), lty = fmaxf(ay1, cy1);
        float rbx = fminf(ax2, cx2), rby = fminf(ay2, cy2);
        float wd = fmaxf(rbx - ltx, 0.0f), ht = fmaxf(rby - lty, 0.0f);
        float inter = wd * ht;
        sup = sup || ((inter / (aar + car - inter + 1e-7f)) > 0.65f);
      }
      if (bon) {
        float ltx = fmaxf(bx1, cx1), lty = fmaxf(by1, cy1);
        float rbx = fminf(bx2, cx2), rby = fminf(by2, cy2);
        float wd = fmaxf(rbx - ltx, 0.0f), ht = fmaxf(rby - lty, 0.0f);
        float inter = wd * ht;
        sup = sup || ((inter / (bar + car - inter + 1e-7f)) > 0.65f);
      }
      bool anysup = __any(sup);
      if (sh.d.val[i] != 0 && !anysup) {
        if (kept < 64) {
          if (lane == kept) { ax1 = cx1; ay1 = cy1; ax2 = cx2; ay2 = cy2; aar = car; aon = 1; }
        } else {
          if (lane == kept - 64) { bx1 = cx1; by1 = cy1; bx2 = cx2; by2 = cy2; bar = car; bon = 1; }
        }
        if (lane == 0) outIdx[kept] = i;
        ++kept;
      }
    }
    if (lane == 0) keptSh = kept;
  }
  __syncthreads();

  // ---- write outputs: num_dets[8] | boxes[8,100,4] | scores[8,100] | labels[8,100] ----
  int kept = keptSh;
  float* o_nd = out;
  float* o_box = out + BB;
  float* o_sc = out + BB + BB * 100 * 4;
  float* o_lb = out + BB + BB * 100 * 4 + BB * 100;
  if (tid == 0) o_nd[b] = (float)kept;
  if (tid < 100) {
    int s = tid;
    float v0 = 0, v1 = 0, v2 = 0, v3 = 0, sv = 0, lv = -1.0f;
    if (s < kept) {
      int i = outIdx[s];
      v0 = sh.d.rx1[i]; v1 = sh.d.ry1[i]; v2 = sh.d.rx2[i]; v3 = sh.d.ry2[i];
      sv = sh.d.sc[i]; lv = (float)sh.d.lab[i];
    }
    float* bo = o_box + ((size_t)b * 100 + s) * 4;
    bo[0] = v0; bo[1] = v1; bo[2] = v2; bo[3] = v3;
    o_sc[b * 100 + s] = sv;
    o_lb[b * 100 + s] = lv;
  }
}

extern "C" void kernel_launch(void* const* d_in, const int* in_sizes, int n_in,
                              void* d_out, int out_size, void* d_ws, size_t ws_size,
                              hipStream_t stream) {
  const float* cls0 = (const float*)d_in[0];  // [8,1203,80,80]
  const float* bb0  = (const float*)d_in[1];  // [8,4,80,80]
  const float* cls1 = (const float*)d_in[2];  // [8,1203,40,40]
  const float* bb1  = (const float*)d_in[3];  // [8,4,40,40]
  const float* cls2 = (const float*)d_in[4];  // [8,1203,20,20]
  const float* bb2  = (const float*)d_in[5];  // [8,4,20,20]

  size_t planeB = (size_t)BB * NANC * sizeof(u64);
  u64* fin = (u64*)d_ws;
  u64* part;
  int nchunk;
  if (ws_size >= 2 * planeB) {
    size_t avail = (ws_size - planeB) / planeB;
    nchunk = (int)(avail < 32 ? avail : 32);
    part = fin + (size_t)BB * NANC;
  } else {
    nchunk = 1;
    part = fin;  // in-place: kreduce reads/writes each element's own slot
  }
  int chunkSz = (CC_TOT + nchunk - 1) / nchunk;
  nchunk = (CC_TOT + chunkSz - 1) / chunkSz;  // no empty chunks

  kmax<<<dim3(10, nchunk, BB), dim3(256), 0, stream>>>(cls0, cls1, cls2, part, chunkSz);
  kreduce<<<dim3((NANC + 255) / 256, BB), dim3(256), 0, stream>>>(part, fin, nchunk);
  knms<<<dim3(BB), dim3(NT), 0, stream>>>(fin, bb0, bb1, bb2, (float*)d_out);
}

// Round 4
// 163.546 us; speedup vs baseline: 2.1591x; 1.0709x over previous
//
#include <hip/hip_runtime.h>
#include <math.h>

#pragma clang fp contract(off)

typedef unsigned long long u64;
typedef unsigned int u32;
typedef float f4 __attribute__((ext_vector_type(4)));
typedef unsigned long long u64x2 __attribute__((ext_vector_type(2)));

#define BB 8
#define CC_TOT 1203
#define NANC 8400
#define NSEL 1000
#define NCAND 1024
#define NT 1024

// order-preserving transform: float -> u32 with unsigned order == float order
__device__ __forceinline__ u32 okey32(float v) {
  u32 b = __float_as_uint(v);
  return (b & 0x80000000u) ? ~b : (b | 0x80000000u);
}

__device__ __forceinline__ float unokey32(u32 ok) {
  u32 fb = (ok & 0x80000000u) ? (ok & 0x7FFFFFFFu) : ~ok;
  return __uint_as_float(fb);
}

// ---------------- kernel 1: per-anchor max/argmax over a class chunk ----------------
// Each thread owns TWO float4 anchor-columns (2 independent loads/iter) and the
// c-loop is unrolled x4 -> up to 8 outstanding 1KB wave-loads (MLP for HBM saturation).
__global__ __launch_bounds__(256) void kmax(const float* __restrict__ cls0,
                                            const float* __restrict__ cls1,
                                            const float* __restrict__ cls2,
                                            u64* __restrict__ part,
                                            int chunkSz) {
  int bx = blockIdx.x;  // 0..3: level0, 4: level1, 5: level2
  const float* cls; int hw4, aoff, xb;
  if (bx < 4)      { cls = cls0; hw4 = 1600; aoff = 0;    xb = bx; }
  else if (bx < 5) { cls = cls1; hw4 = 400;  aoff = 6400; xb = 0; }
  else             { cls = cls2; hw4 = 100;  aoff = 8000; xb = 0; }
  int t = threadIdx.x;
  int e0 = xb * 512 + t;
  if (e0 >= hw4) return;
  int e1 = e0 + 256;
  bool a1 = (e1 < hw4);
  int e1c = a1 ? e1 : e0;  // duplicate-load e0 when e1 is out of range (results discarded)

  int b = blockIdx.z;
  int c0 = blockIdx.y * chunkSz;
  int c1 = c0 + chunkSz; if (c1 > CC_TOT) c1 = CC_TOT;

  const f4* base = (const f4*)cls + (size_t)b * CC_TOT * hw4;
  const f4* p0 = base + (size_t)c0 * hw4 + e0;
  const f4* p1 = base + (size_t)c0 * hw4 + e1c;

  float m00 = -3.4e38f, m01 = -3.4e38f, m02 = -3.4e38f, m03 = -3.4e38f;
  float m10 = -3.4e38f, m11 = -3.4e38f, m12 = -3.4e38f, m13 = -3.4e38f;
  int i00 = c0, i01 = c0, i02 = c0, i03 = c0;
  int i10 = c0, i11 = c0, i12 = c0, i13 = c0;

  #pragma unroll 4
  for (int c = c0; c < c1; ++c) {
    f4 v0 = __builtin_nontemporal_load(p0);
    f4 v1 = __builtin_nontemporal_load(p1);
    if (v0[0] > m00) { m00 = v0[0]; i00 = c; }
    if (v0[1] > m01) { m01 = v0[1]; i01 = c; }
    if (v0[2] > m02) { m02 = v0[2]; i02 = c; }
    if (v0[3] > m03) { m03 = v0[3]; i03 = c; }
    if (v1[0] > m10) { m10 = v1[0]; i10 = c; }
    if (v1[1] > m11) { m11 = v1[1]; i11 = c; }
    if (v1[2] > m12) { m12 = v1[2]; i12 = c; }
    if (v1[3] > m13) { m13 = v1[3]; i13 = c; }
    p0 += hw4; p1 += hw4;
  }

  // pack (okey(maxlogit)<<32 | ~argmax): u64 max => score desc, tie -> smaller class
  u64* plane = part + ((size_t)blockIdx.y * BB + b) * NANC + aoff;
  {
    u64* dst = plane + (size_t)e0 * 4;
    u64x2 s01 = { ((u64)okey32(m00) << 32) | (u64)(u32)~(u32)i00,
                  ((u64)okey32(m01) << 32) | (u64)(u32)~(u32)i01 };
    u64x2 s23 = { ((u64)okey32(m02) << 32) | (u64)(u32)~(u32)i02,
                  ((u64)okey32(m03) << 32) | (u64)(u32)~(u32)i03 };
    __builtin_nontemporal_store(s01, (u64x2*)dst);
    __builtin_nontemporal_store(s23, (u64x2*)dst + 1);
  }
  if (a1) {
    u64* dst = plane + (size_t)e1 * 4;
    u64x2 s01 = { ((u64)okey32(m10) << 32) | (u64)(u32)~(u32)i10,
                  ((u64)okey32(m11) << 32) | (u64)(u32)~(u32)i11 };
    u64x2 s23 = { ((u64)okey32(m12) << 32) | (u64)(u32)~(u32)i12,
                  ((u64)okey32(m13) << 32) | (u64)(u32)~(u32)i13 };
    __builtin_nontemporal_store(s01, (u64x2*)dst);
    __builtin_nontemporal_store(s23, (u64x2*)dst + 1);
  }
}

// ---------------- kernel 1b: reduce partials over chunks + emit final sort key ----------------
// key = (okey(logit) << 32) | ((65535 - anchorIdx) << 16) | label
// bits 16..63 are unique per key (anchor idx unique); label rides in low 16 bits as payload.
__global__ __launch_bounds__(256) void kreduce(const u64* __restrict__ part,
                                               u64* __restrict__ fin, int nchunk) {
  int i = blockIdx.x * 256 + threadIdx.x;
  if (i >= NANC) return;
  int b = blockIdx.y;
  int g = b * NANC + i;
  u64 m = part[g];
  #pragma unroll 4
  for (int ch = 1; ch < nchunk; ++ch) {
    u64 v = __builtin_nontemporal_load(&part[(size_t)ch * (BB * NANC) + g]);
    m = (v > m) ? v : m;
  }
  u32 lab = ~(u32)m;  // argmax class, < 1203
  fin[g] = (m & 0xFFFFFFFF00000000ull) | ((u64)(u32)(0xFFFFu - (u32)i) << 16) | (u64)lab;
}

// ---------------- kernel 2: per-image top-1000 select + rank-sort + NMS + output ----------------
struct DecodeArrays {
  float xo1[NCAND], yo1[NCAND], xo2[NCAND], yo2[NCAND], ar[NCAND];
  float rx1[NCAND], ry1[NCAND], rx2[NCAND], ry2[NCAND], sc[NCAND];
  int lab[NCAND], val[NCAND];
};

__global__ __launch_bounds__(1024) void knms(const u64* __restrict__ fin,
                                             const float* __restrict__ bb0,
                                             const float* __restrict__ bb1,
                                             const float* __restrict__ bb2,
                                             float* __restrict__ out) {
  __shared__ union ShU {
    u64 fk[NANC];      // 67,200 B — dead after gather
    DecodeArrays d;    // 49,152 B — aliases fk
  } sh;
  __shared__ u32 hist[4096];
  __shared__ u32 waveTot[16];
  __shared__ u32 waveSufExcl[16];
  __shared__ u64 prefixSh;
  __shared__ u32 rankSh;
  __shared__ u32 gcnt;
  __shared__ __align__(16) u64 cand[NCAND];
  __shared__ int outIdx[128];
  __shared__ int keptSh;

  int b = blockIdx.x;
  int tid = threadIdx.x;
  int lane = tid & 63;
  int wv = tid >> 6;

  // ---- stage the 8400 pre-built sort keys into LDS ----
  {
    const u64* fk = fin + (size_t)b * NANC;
    for (int i = tid; i < NANC; i += NT) sh.fk[i] = fk[i];
  }
  __syncthreads();

  // ---- exact radix-select of the rank-1000 (descending) key over bits [16,64): 4 x 12-bit ----
  u64 prefix = 0; u32 rank = NSEL;
  for (int pass = 3; pass >= 0; --pass) {
    int shift = 16 + pass * 12;
    for (int i = tid; i < 4096; i += NT) hist[i] = 0;
    __syncthreads();
    u64 hiMask = (pass == 3) ? 0ull : ((~0ull) << (shift + 12));
    for (int i = tid; i < NANC; i += NT) {
      u64 k = sh.fk[i];
      u32 digit = 4096u;  // sentinel: no contribution
      if ((k & hiMask) == (prefix & hiMask)) digit = (u32)((k >> shift) & 4095u);
      // wave-level clustering by 13-bit digit (top pass concentrates into few bins;
      // plain LDS atomics would serialize same-address RMWs)
      u64 peers = ~0ull;
      for (int bit = 0; bit < 13; ++bit) {
        u64 bal = __ballot((digit >> bit) & 1u);
        peers &= ((digit >> bit) & 1u) ? bal : ~bal;
      }
      int leader = __ffsll((unsigned long long)peers) - 1;
      if (digit < 4096u && lane == leader)
        atomicAdd(&hist[digit], (u32)__popcll((unsigned long long)peers));
    }
    __syncthreads();
    // suffix scan over 4096 bins: 4 bins/thread -> intra-wave shfl suffix -> wave totals
    u32 l0 = hist[4 * tid], l1 = hist[4 * tid + 1], l2 = hist[4 * tid + 2], l3 = hist[4 * tid + 3];
    u32 psum = l0 + l1 + l2 + l3;
    u32 x = psum;
    for (int s = 1; s < 64; s <<= 1) {
      u32 v = __shfl_down(x, s);
      if (lane + s < 64) x += v;
    }
    if (lane == 0) waveTot[wv] = x;
    __syncthreads();
    if (tid < 16) {
      u32 y = waveTot[tid];
      u32 z = y;
      for (int s = 1; s < 16; s <<= 1) {
        u32 v = __shfl_down(z, s);
        if (tid + s < 16) z += v;
      }
      waveSufExcl[tid] = z - y;
    }
    __syncthreads();
    u32 S = x + waveSufExcl[wv];   // sum of hist over bins >= 4*tid
    u32 G3 = S - psum;             // count of keys in bins > 4*tid+3
    u32 G2 = G3 + l3;
    u32 G1 = G2 + l2;
    u32 G0 = G1 + l1;
    u32 r = rank;
    if      (G3 < r && G3 + l3 >= r) { prefixSh = prefix | ((u64)(4u * tid + 3) << shift); rankSh = r - G3; }
    else if (G2 < r && G2 + l2 >= r) { prefixSh = prefix | ((u64)(4u * tid + 2) << shift); rankSh = r - G2; }
    else if (G1 < r && G1 + l1 >= r) { prefixSh = prefix | ((u64)(4u * tid + 1) << shift); rankSh = r - G1; }
    else if (G0 < r && G0 + l0 >= r) { prefixSh = prefix | ((u64)(4u * tid + 0) << shift); rankSh = r - G0; }
    __syncthreads();
    prefix = prefixSh; rank = rankSh;
    __syncthreads();
  }
  u64 K = prefix;  // exact rank-1000 key threshold (low 16 bits zero) => count(key >= K) == 1000

  // ---- gather the exact top-1000 (unsorted) into cand ----
  if (tid == 0) gcnt = 0;
  __syncthreads();
  for (int i = tid; i < NANC; i += NT) {
    u64 k = sh.fk[i];
    bool sel = (k >= K);
    u64 mask = __ballot(sel);
    if (mask) {
      int leader = __ffsll((unsigned long long)mask) - 1;
      u32 basep = 0;
      if (lane == leader) basep = atomicAdd(&gcnt, (u32)__popcll((unsigned long long)mask));
      basep = __shfl((int)basep, leader);
      if (sel) {
        u32 off = (u32)__popcll((unsigned long long)(mask & ((1ull << lane) - 1ull)));
        u32 pos = basep + off;
        if (pos < NCAND) cand[pos] = k;
      }
    }
  }
  __syncthreads();  // fk dead from here; sh.d may be written

  // ---- rank-by-comparison sort + decode + scatter by rank ----
  if (tid < NSEL) {
    u64 my = cand[tid];
    int rk = 0;
    const u64x2* candv = (const u64x2*)cand;
    for (int j2 = 0; j2 < NSEL / 2; ++j2) {  // ds_read_b128 broadcast, conflict-free
      u64x2 p = candv[j2];
      rk += (p[0] > my) ? 1 : 0;
      rk += (p[1] > my) ? 1 : 0;
    }
    // decode this candidate
    int label = (int)(u32)(my & 0xFFFFull);
    int idx = 0xFFFF - (int)(u32)((my >> 16) & 0xFFFFull);
    float logit = unokey32((u32)(my >> 32));
    float sc = 1.0f / (1.0f + expf(-logit));

    int w, str, off, hwl; const float* bb;
    if (idx < 6400)      { w = 80; str = 8;  off = 0;    hwl = 6400; bb = bb0; }
    else if (idx < 8000) { w = 40; str = 16; off = 6400; hwl = 1600; bb = bb1; }
    else                 { w = 20; str = 32; off = 8000; hwl = 400;  bb = bb2; }
    int p = idx - off;
    int y = p / w;
    int x = p - y * w;
    float fs = (float)str;
    float px = ((float)x + 0.5f) * fs;
    float py = ((float)y + 0.5f) * fs;
    const float* bp = bb + (size_t)b * 4 * hwl + p;
    float t0 = bp[0] * fs;
    float t1 = bp[hwl] * fs;
    float t2 = bp[2 * hwl] * fs;
    float t3 = bp[3 * hwl] * fs;
    float x1 = px - t0, y1 = py - t1, x2 = px + t2, y2 = py + t3;
    float lo = (float)label * 4096.0f;
    float ox1 = x1 + lo, oy1 = y1 + lo, ox2 = x2 + lo, oy2 = y2 + lo;
    float area = (ox2 - ox1) * (oy2 - oy1);  // ref computes area from OFFSET boxes

    sh.d.xo1[rk] = ox1; sh.d.yo1[rk] = oy1; sh.d.xo2[rk] = ox2; sh.d.yo2[rk] = oy2; sh.d.ar[rk] = area;
    sh.d.rx1[rk] = x1;  sh.d.ry1[rk] = y1;  sh.d.rx2[rk] = x2;  sh.d.ry2[rk] = y2;  sh.d.sc[rk] = sc;
    sh.d.lab[rk] = label;
    sh.d.val[rk] = (sc > 0.25f) ? 1 : 0;
  }
  __syncthreads();

  // ---- greedy NMS, single wave, early exit at 100 kept ----
  if (tid < 64) {
    float ax1 = 0, ay1 = 0, ax2 = 0, ay2 = 0, aar = 0; int aon = 0;
    float bx1 = 0, by1 = 0, bx2 = 0, by2 = 0, bar = 0; int bon = 0;
    int kept = 0;
    for (int i = 0; i < NSEL; ++i) {
      if (kept >= 100) break;
      float cx1 = sh.d.xo1[i], cy1 = sh.d.yo1[i], cx2 = sh.d.xo2[i], cy2 = sh.d.yo2[i], car = sh.d.ar[i];
      bool sup = false;
      if (aon) {
        float ltx = fmaxf(ax1, cx1), lty = fmaxf(ay1, cy1);
        float rbx = fminf(ax2, cx2), rby = fminf(ay2, cy2);
        float wd = fmaxf(rbx - ltx, 0.0f), ht = fmaxf(rby - lty, 0.0f);
        float inter = wd * ht;
        sup = sup || ((inter / (aar + car - inter + 1e-7f)) > 0.65f);
      }
      if (bon) {
        float ltx = fmaxf(bx1, cx1), lty = fmaxf(by1, cy1);
        float rbx = fminf(bx2, cx2), rby = fminf(by2, cy2);
        float wd = fmaxf(rbx - ltx, 0.0f), ht = fmaxf(rby - lty, 0.0f);
        float inter = wd * ht;
        sup = sup || ((inter / (bar + car - inter + 1e-7f)) > 0.65f);
      }
      bool anysup = __any(sup);
      if (sh.d.val[i] != 0 && !anysup) {
        if (kept < 64) {
          if (lane == kept) { ax1 = cx1; ay1 = cy1; ax2 = cx2; ay2 = cy2; aar = car; aon = 1; }
        } else {
          if (lane == kept - 64) { bx1 = cx1; by1 = cy1; bx2 = cx2; by2 = cy2; bar = car; bon = 1; }
        }
        if (lane == 0) outIdx[kept] = i;
        ++kept;
      }
    }
    if (lane == 0) keptSh = kept;
  }
  __syncthreads();

  // ---- write outputs: num_dets[8] | boxes[8,100,4] | scores[8,100] | labels[8,100] ----
  int kept = keptSh;
  float* o_nd = out;
  float* o_box = out + BB;
  float* o_sc = out + BB + BB * 100 * 4;
  float* o_lb = out + BB + BB * 100 * 4 + BB * 100;
  if (tid == 0) o_nd[b] = (float)kept;
  if (tid < 100) {
    int s = tid;
    float v0 = 0, v1 = 0, v2 = 0, v3 = 0, sv = 0, lv = -1.0f;
    if (s < kept) {
      int i = outIdx[s];
      v0 = sh.d.rx1[i]; v1 = sh.d.ry1[i]; v2 = sh.d.rx2[i]; v3 = sh.d.ry2[i];
      sv = sh.d.sc[i]; lv = (float)sh.d.lab[i];
    }
    float* bo = o_box + ((size_t)b * 100 + s) * 4;
    bo[0] = v0; bo[1] = v1; bo[2] = v2; bo[3] = v3;
    o_sc[b * 100 + s] = sv;
    o_lb[b * 100 + s] = lv;
  }
}

extern "C" void kernel_launch(void* const* d_in, const int* in_sizes, int n_in,
                              void* d_out, int out_size, void* d_ws, size_t ws_size,
                              hipStream_t stream) {
  const float* cls0 = (const float*)d_in[0];  // [8,1203,80,80]
  const float* bb0  = (const float*)d_in[1];  // [8,4,80,80]
  const float* cls1 = (const float*)d_in[2];  // [8,1203,40,40]
  const float* bb1  = (const float*)d_in[3];  // [8,4,40,40]
  const float* cls2 = (const float*)d_in[4];  // [8,1203,20,20]
  const float* bb2  = (const float*)d_in[5];  // [8,4,20,20]

  size_t planeB = (size_t)BB * NANC * sizeof(u64);
  u64* fin = (u64*)d_ws;
  u64* part;
  int nchunk;
  if (ws_size >= 2 * planeB) {
    size_t avail = (ws_size - planeB) / planeB;
    nchunk = (int)(avail < 32 ? avail : 32);
    part = fin + (size_t)BB * NANC;
  } else {
    nchunk = 1;
    part = fin;  // in-place: kreduce reads/writes each element's own slot
  }
  int chunkSz = (CC_TOT + nchunk - 1) / nchunk;
  nchunk = (CC_TOT + chunkSz - 1) / chunkSz;  // no empty chunks

  kmax<<<dim3(6, nchunk, BB), dim3(256), 0, stream>>>(cls0, cls1, cls2, part, chunkSz);
  kreduce<<<dim3((NANC + 255) / 256, BB), dim3(256), 0, stream>>>(part, fin, nchunk);
  knms<<<dim3(BB), dim3(NT), 0, stream>>>(fin, bb0, bb1, bb2, (float*)d_out);
}